// Round 1
// baseline (981.995 us; speedup 1.0000x reference)
//
#include <hip/hip_runtime.h>

static constexpr int NN = 100000;
static constexpr int NE = 1600000;
static constexpr int DD = 128;
static constexpr int SCAN_CHUNK = 1024;
static constexpr int NB = (NN + SCAN_CHUNK - 1) / SCAN_CHUNK; // 98

// ws layout in 4-byte words
static constexpr int OFF_DEG  = 0;                 // NN ints
static constexpr int OFF_OFFS = NN;                // NN+1 ints
static constexpr int OFF_CUR  = 2*NN + 2;          // NN ints
static constexpr int OFF_PART = 3*NN + 8;          // 256 ints
static constexpr int OFF_INV  = 3*NN + 512;        // NN floats
static constexpr int OFF_SS   = 4*NN + 512;        // NE ints
static constexpr int OFF_HN   = 4*NN + 512 + NE;   // NN*DD floats (16B-aligned word idx)
static constexpr int ZERO_N   = 3*NN + 264;        // covers deg, offs, cursor, partials

__global__ void k_zero(int* ws) {
  int i = blockIdx.x * blockDim.x + threadIdx.x;
  if (i < ZERO_N) ws[i] = 0;
}

__global__ void k_hist(const int* __restrict__ dst, int* __restrict__ deg) {
  int e = blockIdx.x * blockDim.x + threadIdx.x;
  if (e < NE) atomicAdd(&deg[dst[e]], 1);
}

__global__ void k_scan1(const int* __restrict__ deg, int* __restrict__ offs,
                        int* __restrict__ partials) {
  __shared__ int sc[256];
  int b = blockIdx.x, t = threadIdx.x;
  int base = b * SCAN_CHUNK + t * 4;
  int d0 = (base + 0 < NN) ? deg[base + 0] : 0;
  int d1 = (base + 1 < NN) ? deg[base + 1] : 0;
  int d2 = (base + 2 < NN) ? deg[base + 2] : 0;
  int d3 = (base + 3 < NN) ? deg[base + 3] : 0;
  int s = d0 + d1 + d2 + d3;
  sc[t] = s;
  __syncthreads();
  for (int off = 1; off < 256; off <<= 1) {
    int v = (t >= off) ? sc[t - off] : 0;
    __syncthreads();
    sc[t] += v;
    __syncthreads();
  }
  int ebase = sc[t] - s;  // exclusive base for this thread within block
  if (base + 0 < NN) offs[base + 0] = ebase;
  if (base + 1 < NN) offs[base + 1] = ebase + d0;
  if (base + 2 < NN) offs[base + 2] = ebase + d0 + d1;
  if (base + 3 < NN) offs[base + 3] = ebase + d0 + d1 + d2;
  if (t == 255) partials[b] = sc[255];
}

__global__ void k_scan2(int* __restrict__ partials) {
  __shared__ int sc[128];
  int t = threadIdx.x;
  int p = (t < NB) ? partials[t] : 0;
  sc[t] = p;
  __syncthreads();
  for (int off = 1; off < 128; off <<= 1) {
    int v = (t >= off) ? sc[t - off] : 0;
    __syncthreads();
    sc[t] += v;
    __syncthreads();
  }
  if (t < NB) partials[t] = sc[t] - p;  // exclusive scan of block totals
}

__global__ void k_scan3(const int* __restrict__ deg, int* __restrict__ offs,
                        const int* __restrict__ partials, float* __restrict__ inv_deg) {
  int i = blockIdx.x * blockDim.x + threadIdx.x;
  if (i < NN) {
    offs[i] += partials[i / SCAN_CHUNK];
    int d = deg[i];
    inv_deg[i] = 1.0f / (float)(d > 1 ? d : 1);
  }
  if (i == 0) offs[NN] = NE;
}

__global__ void k_scatter(const int* __restrict__ src, const int* __restrict__ dst,
                          const int* __restrict__ offs, int* __restrict__ cursor,
                          int* __restrict__ ss) {
  int e = blockIdx.x * blockDim.x + threadIdx.x;
  if (e < NE) {
    int d = dst[e];
    int pos = offs[d] + atomicAdd(&cursor[d], 1);
    ss[pos] = src[e];
  }
}

// one wave per node: mean of in-neighbor rows
__global__ void k_agg(const float* __restrict__ h, const int* __restrict__ offs,
                      const int* __restrict__ ss, const float* __restrict__ inv_deg,
                      float* __restrict__ hN) {
  int wid  = (blockIdx.x * blockDim.x + threadIdx.x) >> 6;
  int lane = threadIdx.x & 63;
  int nw   = (gridDim.x * blockDim.x) >> 6;
  for (int v = wid; v < NN; v += nw) {
    int beg = offs[v], end = offs[v + 1];
    float ax = 0.f, ay = 0.f, bx = 0.f, by = 0.f;
    float cx = 0.f, cy = 0.f, dx = 0.f, dy = 0.f;
    int e = beg;
    for (; e + 3 < end; e += 4) {
      int s0 = ss[e], s1 = ss[e + 1], s2 = ss[e + 2], s3 = ss[e + 3];
      float2 v0 = *(const float2*)(h + (size_t)s0 * DD + lane * 2);
      float2 v1 = *(const float2*)(h + (size_t)s1 * DD + lane * 2);
      float2 v2 = *(const float2*)(h + (size_t)s2 * DD + lane * 2);
      float2 v3 = *(const float2*)(h + (size_t)s3 * DD + lane * 2);
      ax += v0.x; ay += v0.y; bx += v1.x; by += v1.y;
      cx += v2.x; cy += v2.y; dx += v3.x; dy += v3.y;
    }
    for (; e < end; ++e) {
      int s0 = ss[e];
      float2 v0 = *(const float2*)(h + (size_t)s0 * DD + lane * 2);
      ax += v0.x; ay += v0.y;
    }
    float w = inv_deg[v];
    float2 r;
    r.x = (ax + bx + cx + dx) * w;
    r.y = (ay + by + cy + dy) * w;
    *(float2*)(hN + (size_t)v * DD + lane * 2) = r;
  }
}

// h_out = relu(h_in @ Ws + hN @ Wn + bias); safe in-place (block reads only its own rows)
__global__ __launch_bounds__(256) void k_gemm(
    const float* h_in, const float* __restrict__ hN,
    const float* __restrict__ Ws, const float* __restrict__ Wn,
    const float* __restrict__ bias, float* h_out) {
  __shared__ float As[64][33];
  __shared__ float Wsh[32][128];
  int t = threadIdx.x;
  int tx = t & 15, ty = t >> 4;
  int row0 = blockIdx.x * 64;
  float acc[4][8];
#pragma unroll
  for (int i = 0; i < 4; ++i)
#pragma unroll
    for (int j = 0; j < 8; ++j) acc[i][j] = 0.f;

  for (int ks = 0; ks < 2 * DD; ks += 32) {
    const float* srcA = (ks < DD) ? h_in : hN;
    const float* srcW = (ks < DD) ? Ws : Wn;
    int k0 = ks & (DD - 1);
    // stage A: 64 rows x 32 cols
#pragma unroll
    for (int i = 0; i < 2; ++i) {
      int li = t + i * 256;          // 0..511 float4 slots
      int r = li >> 3;
      int c = (li & 7) << 2;
      int grow = row0 + r;
      float4 v4 = make_float4(0.f, 0.f, 0.f, 0.f);
      if (grow < NN) v4 = *(const float4*)(srcA + (size_t)grow * DD + k0 + c);
      As[r][c + 0] = v4.x; As[r][c + 1] = v4.y;
      As[r][c + 2] = v4.z; As[r][c + 3] = v4.w;
    }
    // stage W: 32 rows x 128 cols (contiguous)
    const float* wp = srcW + k0 * DD;
#pragma unroll
    for (int i = 0; i < 4; ++i) {
      int li = t + i * 256;          // 0..1023 float4 slots
      int r = li >> 5;
      int c = (li & 31) << 2;
      *(float4*)(&Wsh[r][c]) = *(const float4*)(wp + r * DD + c);
    }
    __syncthreads();
#pragma unroll
    for (int kk = 0; kk < 32; ++kk) {
      float a[4];
#pragma unroll
      for (int i = 0; i < 4; ++i) a[i] = As[ty * 4 + i][kk];
      float wv[8];
      *(float4*)(&wv[0]) = *(const float4*)(&Wsh[kk][tx * 8]);
      *(float4*)(&wv[4]) = *(const float4*)(&Wsh[kk][tx * 8 + 4]);
#pragma unroll
      for (int i = 0; i < 4; ++i)
#pragma unroll
        for (int j = 0; j < 8; ++j) acc[i][j] += a[i] * wv[j];
    }
    __syncthreads();
  }
  float bv[8];
#pragma unroll
  for (int j = 0; j < 8; ++j) bv[j] = bias[tx * 8 + j];
#pragma unroll
  for (int i = 0; i < 4; ++i) {
    int r = row0 + ty * 4 + i;
    if (r < NN) {
      float4 o0, o1;
      o0.x = fmaxf(acc[i][0] + bv[0], 0.f);
      o0.y = fmaxf(acc[i][1] + bv[1], 0.f);
      o0.z = fmaxf(acc[i][2] + bv[2], 0.f);
      o0.w = fmaxf(acc[i][3] + bv[3], 0.f);
      o1.x = fmaxf(acc[i][4] + bv[4], 0.f);
      o1.y = fmaxf(acc[i][5] + bv[5], 0.f);
      o1.z = fmaxf(acc[i][6] + bv[6], 0.f);
      o1.w = fmaxf(acc[i][7] + bv[7], 0.f);
      *(float4*)(h_out + (size_t)r * DD + tx * 8) = o0;
      *(float4*)(h_out + (size_t)r * DD + tx * 8 + 4) = o1;
    }
  }
}

extern "C" void kernel_launch(void* const* d_in, const int* in_sizes, int n_in,
                              void* d_out, int out_size, void* d_ws, size_t ws_size,
                              hipStream_t stream) {
  const float* x    = (const float*)d_in[0];
  const float* Ws   = (const float*)d_in[1];
  const float* Wn   = (const float*)d_in[2];
  const float* bias = (const float*)d_in[3];
  const int*   src  = (const int*)d_in[4];
  const int*   dst  = (const int*)d_in[5];
  float* out = (float*)d_out;

  int* ws       = (int*)d_ws;
  int* deg      = ws + OFF_DEG;
  int* offs     = ws + OFF_OFFS;
  int* cur      = ws + OFF_CUR;
  int* part     = ws + OFF_PART;
  float* inv    = (float*)(ws + OFF_INV);
  int* ssorted  = ws + OFF_SS;
  float* hN     = (float*)(ws + OFF_HN);

  // --- build CSR (dst -> sorted src list) once per call ---
  k_zero<<<(ZERO_N + 255) / 256, 256, 0, stream>>>(ws);
  k_hist<<<(NE + 255) / 256, 256, 0, stream>>>(dst, deg);
  k_scan1<<<NB, 256, 0, stream>>>(deg, offs, part);
  k_scan2<<<1, 128, 0, stream>>>(part);
  k_scan3<<<(NN + 255) / 256, 256, 0, stream>>>(deg, offs, part, inv);
  k_scatter<<<(NE + 255) / 256, 256, 0, stream>>>(src, dst, offs, cur, ssorted);

  // --- 3 SAGE layers; GEMM is in-place in d_out after layer 0 ---
  const float* hin = x;
  for (int l = 0; l < 3; ++l) {
    k_agg<<<1024, 256, 0, stream>>>(hin, offs, ssorted, inv, hN);
    k_gemm<<<(NN + 63) / 64, 256, 0, stream>>>(hin, hN, Ws + l * DD * DD,
                                               Wn + l * DD * DD, bias + l * DD, out);
    hin = out;
  }
}

// Round 2
// 620.371 us; speedup vs baseline: 1.5829x; 1.5829x over previous
//
#include <hip/hip_runtime.h>

typedef __attribute__((ext_vector_type(8))) short short8;
typedef __attribute__((ext_vector_type(4))) float f32x4;

static constexpr int NN = 100000;
static constexpr int NE = 1600000;
static constexpr int DD = 128;
static constexpr int SCAN_CHUNK = 1024;
static constexpr int NB = (NN + SCAN_CHUNK - 1) / SCAN_CHUNK; // 98

// ws layout in 4-byte words
static constexpr int OFF_DEG  = 0;                 // NN ints
static constexpr int OFF_OFFS = NN;                // NN+1 ints
static constexpr int OFF_CUR  = 2*NN + 2;          // NN ints (reused for Wt after scatter)
static constexpr int OFF_WT   = 2*NN + 4;          // 3*256*128 bf16 = 49152 words (16B aligned)
static constexpr int OFF_PART = 3*NN + 8;          // 256 ints
static constexpr int OFF_INV  = 3*NN + 512;        // NN floats
static constexpr int OFF_SS   = 4*NN + 512;        // NE ints
static constexpr int OFF_HB   = 4*NN + 512 + NE;   // NN*64 words: h bf16 [NN][128]
static constexpr int OFF_HNB  = OFF_HB + NN*64;    // NN*64 words: h_neigh bf16 [NN][128]
static constexpr int ZERO_N   = 3*NN + 264;        // covers deg, offs, cursor, partials

__device__ inline ushort f2b(float f) {
  uint u = __builtin_bit_cast(uint, f);
  uint r = (u + 0x7fffu + ((u >> 16) & 1u)) >> 16;
  return (ushort)r;
}
__device__ inline float b2f(ushort b) {
  uint u = ((uint)b) << 16;
  return __builtin_bit_cast(float, u);
}

__global__ void k_zero(int* ws) {
  int i = blockIdx.x * blockDim.x + threadIdx.x;
  if (i < ZERO_N) ws[i] = 0;
}

__global__ void k_x2b(const float* __restrict__ x, ushort* __restrict__ hb) {
  int i = blockIdx.x * blockDim.x + threadIdx.x;   // each handles 2 elems
  if (i < NN * (DD / 2)) {
    float2 v = *(const float2*)(x + (size_t)i * 2);
    uint p = (uint)f2b(v.x) | ((uint)f2b(v.y) << 16);
    *(uint*)(hb + (size_t)i * 2) = p;
  }
}

__global__ void k_hist(const int* __restrict__ dst, int* __restrict__ deg) {
  int e = blockIdx.x * blockDim.x + threadIdx.x;
  if (e < NE) atomicAdd(&deg[dst[e]], 1);
}

__global__ void k_scan1(const int* __restrict__ deg, int* __restrict__ offs,
                        int* __restrict__ partials) {
  __shared__ int sc[256];
  int b = blockIdx.x, t = threadIdx.x;
  int base = b * SCAN_CHUNK + t * 4;
  int d0 = (base + 0 < NN) ? deg[base + 0] : 0;
  int d1 = (base + 1 < NN) ? deg[base + 1] : 0;
  int d2 = (base + 2 < NN) ? deg[base + 2] : 0;
  int d3 = (base + 3 < NN) ? deg[base + 3] : 0;
  int s = d0 + d1 + d2 + d3;
  sc[t] = s;
  __syncthreads();
  for (int off = 1; off < 256; off <<= 1) {
    int v = (t >= off) ? sc[t - off] : 0;
    __syncthreads();
    sc[t] += v;
    __syncthreads();
  }
  int ebase = sc[t] - s;
  if (base + 0 < NN) offs[base + 0] = ebase;
  if (base + 1 < NN) offs[base + 1] = ebase + d0;
  if (base + 2 < NN) offs[base + 2] = ebase + d0 + d1;
  if (base + 3 < NN) offs[base + 3] = ebase + d0 + d1 + d2;
  if (t == 255) partials[b] = sc[255];
}

__global__ void k_scan2(int* __restrict__ partials) {
  __shared__ int sc[128];
  int t = threadIdx.x;
  int p = (t < NB) ? partials[t] : 0;
  sc[t] = p;
  __syncthreads();
  for (int off = 1; off < 128; off <<= 1) {
    int v = (t >= off) ? sc[t - off] : 0;
    __syncthreads();
    sc[t] += v;
    __syncthreads();
  }
  if (t < NB) partials[t] = sc[t] - p;
}

__global__ void k_scan3(const int* __restrict__ deg, int* __restrict__ offs,
                        const int* __restrict__ partials, float* __restrict__ inv_deg) {
  int i = blockIdx.x * blockDim.x + threadIdx.x;
  if (i < NN) {
    offs[i] += partials[i / SCAN_CHUNK];
    int d = deg[i];
    inv_deg[i] = 1.0f / (float)(d > 1 ? d : 1);
  }
  if (i == 0) offs[NN] = NE;
}

__global__ void k_scatter(const int* __restrict__ src, const int* __restrict__ dst,
                          const int* __restrict__ offs, int* __restrict__ cursor,
                          int* __restrict__ ss) {
  int e = blockIdx.x * blockDim.x + threadIdx.x;
  if (e < NE) {
    int d = dst[e];
    int pos = offs[d] + atomicAdd(&cursor[d], 1);
    ss[pos] = src[e];
  }
}

// W^T concat: Wt[l][col][k], k<128 -> Ws[l][k][col], k>=128 -> Wn[l][k-128][col]
__global__ void k_wt(const float* __restrict__ Ws, const float* __restrict__ Wn,
                     ushort* __restrict__ Wt) {
  int i = blockIdx.x * blockDim.x + threadIdx.x;
  if (i < 3 * 128 * 256) {
    int l = i >> 15;
    int rem = i & 32767;
    int col = rem >> 8;
    int k = rem & 255;
    float v = (k < 128) ? Ws[((size_t)l * 128 + k) * 128 + col]
                        : Wn[((size_t)l * 128 + (k - 128)) * 128 + col];
    Wt[i] = f2b(v);
  }
}

// one wave per node: mean of in-neighbor bf16 rows, fp32 accumulate, bf16 out
__global__ void k_agg_bf(const ushort* __restrict__ h, const int* __restrict__ offs,
                         const int* __restrict__ ss, const float* __restrict__ inv_deg,
                         ushort* __restrict__ hN) {
  int wid  = (blockIdx.x * blockDim.x + threadIdx.x) >> 6;
  int lane = threadIdx.x & 63;
  int nw   = (gridDim.x * blockDim.x) >> 6;
  for (int v = wid; v < NN; v += nw) {
    int beg = offs[v], end = offs[v + 1];
    float sx0 = 0.f, sy0 = 0.f, sx1 = 0.f, sy1 = 0.f;
    float sx2 = 0.f, sy2 = 0.f, sx3 = 0.f, sy3 = 0.f;
    float sx4 = 0.f, sy4 = 0.f, sx5 = 0.f, sy5 = 0.f;
    float sx6 = 0.f, sy6 = 0.f, sx7 = 0.f, sy7 = 0.f;
    int e = beg;
    for (; e + 7 < end; e += 8) {
      uint u0 = *(const uint*)(h + (size_t)ss[e + 0] * DD + lane * 2);
      uint u1 = *(const uint*)(h + (size_t)ss[e + 1] * DD + lane * 2);
      uint u2 = *(const uint*)(h + (size_t)ss[e + 2] * DD + lane * 2);
      uint u3 = *(const uint*)(h + (size_t)ss[e + 3] * DD + lane * 2);
      uint u4 = *(const uint*)(h + (size_t)ss[e + 4] * DD + lane * 2);
      uint u5 = *(const uint*)(h + (size_t)ss[e + 5] * DD + lane * 2);
      uint u6 = *(const uint*)(h + (size_t)ss[e + 6] * DD + lane * 2);
      uint u7 = *(const uint*)(h + (size_t)ss[e + 7] * DD + lane * 2);
      sx0 += b2f((ushort)u0); sy0 += b2f((ushort)(u0 >> 16));
      sx1 += b2f((ushort)u1); sy1 += b2f((ushort)(u1 >> 16));
      sx2 += b2f((ushort)u2); sy2 += b2f((ushort)(u2 >> 16));
      sx3 += b2f((ushort)u3); sy3 += b2f((ushort)(u3 >> 16));
      sx4 += b2f((ushort)u4); sy4 += b2f((ushort)(u4 >> 16));
      sx5 += b2f((ushort)u5); sy5 += b2f((ushort)(u5 >> 16));
      sx6 += b2f((ushort)u6); sy6 += b2f((ushort)(u6 >> 16));
      sx7 += b2f((ushort)u7); sy7 += b2f((ushort)(u7 >> 16));
    }
    for (; e < end; ++e) {
      uint u0 = *(const uint*)(h + (size_t)ss[e] * DD + lane * 2);
      sx0 += b2f((ushort)u0); sy0 += b2f((ushort)(u0 >> 16));
    }
    float w = inv_deg[v];
    float fx = ((sx0 + sx1) + (sx2 + sx3)) + ((sx4 + sx5) + (sx6 + sx7));
    float fy = ((sy0 + sy1) + (sy2 + sy3)) + ((sy4 + sy5) + (sy6 + sy7));
    fx *= w; fy *= w;
    uint p = (uint)f2b(fx) | ((uint)f2b(fy) << 16);
    *(uint*)(hN + (size_t)v * DD + lane * 2) = p;
  }
}

// h_out = relu([hA|hN] @ Wt^T + bias); MFMA bf16, fp32 acc; in-place safe on hA.
// Block: 256 thr = 4 waves, 128 rows; wave w owns rows [row0+32w, +32).
__global__ __launch_bounds__(256) void k_gemm_mfma(
    const ushort* __restrict__ hA, const ushort* __restrict__ hNb,
    const ushort* __restrict__ Wt, const float* __restrict__ bias,
    ushort* __restrict__ hOutB, float* __restrict__ outF, int writeF) {
  int w = threadIdx.x >> 6;
  int lane = threadIdx.x & 63;
  int row0 = blockIdx.x * 128 + w * 32;
  int r = lane & 15;
  int kg = lane >> 4;

  f32x4 acc[2][8];
#pragma unroll
  for (int mt = 0; mt < 2; ++mt)
#pragma unroll
    for (int nt = 0; nt < 8; ++nt) acc[mt][nt] = (f32x4)0.f;

  int ra0 = row0 + r;       if (ra0 >= NN) ra0 = NN - 1;
  int ra1 = row0 + 16 + r;  if (ra1 >= NN) ra1 = NN - 1;

#pragma unroll
  for (int kt = 0; kt < 8; ++kt) {
    const ushort* hs = (kt < 4) ? hA : hNb;
    int kk = (kt & 3) * 32 + kg * 8;
    short8 a0 = *(const short8*)(hs + (size_t)ra0 * DD + kk);
    short8 a1 = *(const short8*)(hs + (size_t)ra1 * DD + kk);
    int kw = kt * 32 + kg * 8;
#pragma unroll
    for (int nt = 0; nt < 8; ++nt) {
      short8 b = *(const short8*)(Wt + (size_t)(nt * 16 + r) * 256 + kw);
      acc[0][nt] = __builtin_amdgcn_mfma_f32_16x16x32_bf16(a0, b, acc[0][nt], 0, 0, 0);
      acc[1][nt] = __builtin_amdgcn_mfma_f32_16x16x32_bf16(a1, b, acc[1][nt], 0, 0, 0);
    }
  }

  float bv[8];
#pragma unroll
  for (int nt = 0; nt < 8; ++nt) bv[nt] = bias[nt * 16 + r];

  int kg4 = kg * 4;
#pragma unroll
  for (int mt = 0; mt < 2; ++mt) {
#pragma unroll
    for (int j = 0; j < 4; ++j) {
      int row = row0 + mt * 16 + kg4 + j;
      if (row < NN) {
#pragma unroll
        for (int nt = 0; nt < 8; ++nt) {
          float val = fmaxf(acc[mt][nt][j] + bv[nt], 0.f);
          hOutB[(size_t)row * DD + nt * 16 + r] = f2b(val);
          if (writeF) outF[(size_t)row * DD + nt * 16 + r] = val;
        }
      }
    }
  }
}

extern "C" void kernel_launch(void* const* d_in, const int* in_sizes, int n_in,
                              void* d_out, int out_size, void* d_ws, size_t ws_size,
                              hipStream_t stream) {
  const float* x    = (const float*)d_in[0];
  const float* Ws   = (const float*)d_in[1];
  const float* Wn   = (const float*)d_in[2];
  const float* bias = (const float*)d_in[3];
  const int*   src  = (const int*)d_in[4];
  const int*   dst  = (const int*)d_in[5];
  float* out = (float*)d_out;

  int* ws      = (int*)d_ws;
  int* deg     = ws + OFF_DEG;
  int* offs    = ws + OFF_OFFS;
  int* cur     = ws + OFF_CUR;
  ushort* Wt   = (ushort*)(ws + OFF_WT);
  int* part    = ws + OFF_PART;
  float* inv   = (float*)(ws + OFF_INV);
  int* ssorted = ws + OFF_SS;
  ushort* hB   = (ushort*)(ws + OFF_HB);
  ushort* hNb  = (ushort*)(ws + OFF_HNB);

  // CSR build + input conversion
  k_zero<<<(ZERO_N + 255) / 256, 256, 0, stream>>>(ws);
  k_x2b<<<(NN * (DD / 2) + 255) / 256, 256, 0, stream>>>(x, hB);
  k_hist<<<(NE + 255) / 256, 256, 0, stream>>>(dst, deg);
  k_scan1<<<NB, 256, 0, stream>>>(deg, offs, part);
  k_scan2<<<1, 128, 0, stream>>>(part);
  k_scan3<<<(NN + 255) / 256, 256, 0, stream>>>(deg, offs, part, inv);
  k_scatter<<<(NE + 255) / 256, 256, 0, stream>>>(src, dst, offs, cur, ssorted);
  k_wt<<<(3 * 128 * 256 + 255) / 256, 256, 0, stream>>>(Ws, Wn, Wt);  // after scatter: Wt aliases cursor

  // 3 SAGE layers, h kept in bf16; final layer also writes fp32 out
  for (int l = 0; l < 3; ++l) {
    k_agg_bf<<<2048, 256, 0, stream>>>(hB, offs, ssorted, inv, hNb);
    k_gemm_mfma<<<(NN + 127) / 128, 256, 0, stream>>>(
        hB, hNb, Wt + (size_t)l * 256 * 128, bias + l * DD, hB, out, l == 2 ? 1 : 0);
  }
}

// Round 3
// 609.797 us; speedup vs baseline: 1.6104x; 1.0173x over previous
//
#include <hip/hip_runtime.h>

typedef __attribute__((ext_vector_type(8))) short short8;
typedef __attribute__((ext_vector_type(4))) float f32x4;

static constexpr int NN = 100000;
static constexpr int NE = 1600000;
static constexpr int DD = 128;
static constexpr int SCAN_CHUNK = 1024;
static constexpr int NB = (NN + SCAN_CHUNK - 1) / SCAN_CHUNK; // 98
static constexpr int NBUCK = 98;                              // dst >> 10
static constexpr int CAP = 18432;                             // mean 16384 + 16 sigma

// ws layout in 4-byte words
static constexpr int OFF_DEG  = 0;                    // NN
static constexpr int OFF_OFFS = NN;                   // NN+1
static constexpr int OFF_CUR  = 2*NN + 2;             // NN
static constexpr int OFF_GCUR = 3*NN + 8;             // 128
static constexpr int OFF_PART = 3*NN + 136;           // 128
static constexpr int OFF_INV  = 3*NN + 264;           // NN
static constexpr int OFF_WT   = 4*NN + 264;           // 3*256*128 bf16 = 49152 words (16B aligned)
static constexpr int OFF_SS   = 4*NN + 49416;         // NE
static constexpr int OFF_HB   = 4*NN + 49416 + NE;    // NN*64 (h bf16)
static constexpr int OFF_HNB  = OFF_HB + NN*64;       // NN*64 (h_neigh bf16; ebuf aliases this)
static constexpr int ZERO_BASE = OFF_CUR;             // zero cur + gcur (+gap)
static constexpr int ZERO_N    = NN + 134;

__device__ inline ushort f2b(float f) {
  uint u = __builtin_bit_cast(uint, f);
  uint r = (u + 0x7fffu + ((u >> 16) & 1u)) >> 16;
  return (ushort)r;
}
__device__ inline float b2f(ushort b) {
  uint u = ((uint)b) << 16;
  return __builtin_bit_cast(float, u);
}

__global__ void k_zero(int* p) {
  int i = blockIdx.x * blockDim.x + threadIdx.x;
  if (i < ZERO_N) p[i] = 0;
}

__global__ void k_x2b(const float* __restrict__ x, ushort* __restrict__ hb) {
  int i = blockIdx.x * blockDim.x + threadIdx.x;
  if (i < NN * (DD / 2)) {
    float2 v = *(const float2*)(x + (size_t)i * 2);
    uint p = (uint)f2b(v.x) | ((uint)f2b(v.y) << 16);
    *(uint*)(hb + (size_t)i * 2) = p;
  }
}

// W^T concat: Wt[l][col][k], k<128 -> Ws[l][k][col], k>=128 -> Wn[l][k-128][col]
__global__ void k_wt(const float* __restrict__ Ws, const float* __restrict__ Wn,
                     ushort* __restrict__ Wt) {
  int i = blockIdx.x * blockDim.x + threadIdx.x;
  if (i < 3 * 128 * 256) {
    int l = i >> 15;
    int rem = i & 32767;
    int col = rem >> 8;
    int k = rem & 255;
    float v = (k < 128) ? Ws[((size_t)l * 128 + k) * 128 + col]
                        : Wn[((size_t)l * 128 + (k - 128)) * 128 + col];
    Wt[i] = f2b(v);
  }
}

// Pass 1: bucket edges by dst>>10 into fixed-stride regions of ebuf.
__global__ __launch_bounds__(256) void k_bucket(const int* __restrict__ src,
                                                const int* __restrict__ dst,
                                                int* __restrict__ gcur,
                                                int2* __restrict__ ebuf) {
  __shared__ int cnt[NBUCK], base[NBUCK];
  int t = threadIdx.x;
  int b0 = blockIdx.x * 4096;
  if (t < NBUCK) cnt[t] = 0;
  __syncthreads();
  int dv[16], pv[16];
#pragma unroll
  for (int j = 0; j < 16; ++j) {
    int idx = b0 + j * 256 + t;
    if (idx < NE) {
      int d = dst[idx];
      dv[j] = d;
      pv[j] = atomicAdd(&cnt[d >> 10], 1);
    } else dv[j] = -1;
  }
  __syncthreads();
  if (t < NBUCK) base[t] = atomicAdd(&gcur[t], cnt[t]);
  __syncthreads();
#pragma unroll
  for (int j = 0; j < 16; ++j) {
    if (dv[j] >= 0) {
      int idx = b0 + j * 256 + t;
      int b = dv[j] >> 10;
      int2 pr; pr.x = src[idx]; pr.y = dv[j];
      ebuf[(size_t)b * CAP + base[b] + pv[j]] = pr;
    }
  }
}

// Pass 2: per-bucket LDS histogram -> deg (no global atomics)
__global__ __launch_bounds__(256) void k_hist2(const int2* __restrict__ ebuf,
                                               const int* __restrict__ gcur,
                                               int* __restrict__ deg) {
  __shared__ int hist[1024];
  int b = blockIdx.x, t = threadIdx.x;
#pragma unroll
  for (int j = 0; j < 4; ++j) hist[t + j * 256] = 0;
  __syncthreads();
  int n = gcur[b];
  const int2* eb = ebuf + (size_t)b * CAP;
  for (int i = t; i < n; i += 256) atomicAdd(&hist[eb[i].y & 1023], 1);
  __syncthreads();
#pragma unroll
  for (int j = 0; j < 4; ++j) {
    int node = b * 1024 + t + j * 256;
    if (node < NN) deg[node] = hist[t + j * 256];
  }
}

__global__ void k_scan1(const int* __restrict__ deg, int* __restrict__ offs,
                        int* __restrict__ partials) {
  __shared__ int sc[256];
  int b = blockIdx.x, t = threadIdx.x;
  int base = b * SCAN_CHUNK + t * 4;
  int d0 = (base + 0 < NN) ? deg[base + 0] : 0;
  int d1 = (base + 1 < NN) ? deg[base + 1] : 0;
  int d2 = (base + 2 < NN) ? deg[base + 2] : 0;
  int d3 = (base + 3 < NN) ? deg[base + 3] : 0;
  int s = d0 + d1 + d2 + d3;
  sc[t] = s;
  __syncthreads();
  for (int off = 1; off < 256; off <<= 1) {
    int v = (t >= off) ? sc[t - off] : 0;
    __syncthreads();
    sc[t] += v;
    __syncthreads();
  }
  int ebase = sc[t] - s;
  if (base + 0 < NN) offs[base + 0] = ebase;
  if (base + 1 < NN) offs[base + 1] = ebase + d0;
  if (base + 2 < NN) offs[base + 2] = ebase + d0 + d1;
  if (base + 3 < NN) offs[base + 3] = ebase + d0 + d1 + d2;
  if (t == 255) partials[b] = sc[255];
}

__global__ void k_scan2(int* __restrict__ partials) {
  __shared__ int sc[128];
  int t = threadIdx.x;
  int p = (t < NB) ? partials[t] : 0;
  sc[t] = p;
  __syncthreads();
  for (int off = 1; off < 128; off <<= 1) {
    int v = (t >= off) ? sc[t - off] : 0;
    __syncthreads();
    sc[t] += v;
    __syncthreads();
  }
  if (t < NB) partials[t] = sc[t] - p;
}

__global__ void k_scan3(const int* __restrict__ deg, int* __restrict__ offs,
                        const int* __restrict__ partials, float* __restrict__ inv_deg) {
  int i = blockIdx.x * blockDim.x + threadIdx.x;
  if (i < NN) {
    offs[i] += partials[i / SCAN_CHUNK];
    int d = deg[i];
    inv_deg[i] = 1.0f / (float)(d > 1 ? d : 1);
  }
  if (i == 0) offs[NN] = NE;
}

// Pass 3: scatter src into CSR; reads bucketed (writes land in ~64KB window -> L2-local)
__global__ __launch_bounds__(256) void k_scatter2(const int2* __restrict__ ebuf,
                                                  const int* __restrict__ gcur,
                                                  const int* __restrict__ offs,
                                                  int* __restrict__ cur,
                                                  int* __restrict__ ss) {
  int b = blockIdx.x >> 2, q = blockIdx.x & 3, t = threadIdx.x;
  int n = gcur[b];
  int lo = (int)((long long)n * q / 4), hi = (int)((long long)n * (q + 1) / 4);
  const int2* eb = ebuf + (size_t)b * CAP;
  for (int i = lo + t; i < hi; i += 256) {
    int2 e = eb[i];
    int pos = offs[e.y] + atomicAdd(&cur[e.y], 1);
    ss[pos] = e.x;
  }
}

// 2 nodes per wave (32 lanes/row, uint2 = 4 bf16/lane), fp32 accumulate
__global__ void k_agg2(const ushort* __restrict__ h, const int* __restrict__ offs,
                       const int* __restrict__ ss, const float* __restrict__ inv_deg,
                       ushort* __restrict__ hN) {
  int gid = blockIdx.x * blockDim.x + threadIdx.x;
  int wid = gid >> 6;
  int lane = threadIdx.x & 63;
  int half = lane >> 5, l32 = lane & 31;
  int nw = (gridDim.x * blockDim.x) >> 6;
  for (int vp = wid; vp < NN / 2; vp += nw) {
    int v = vp * 2 + half;
    int beg = offs[v], end = offs[v + 1];
    float a0=0,a1=0,a2=0,a3=0, b0=0,b1=0,b2=0,b3=0;
    float c0=0,c1=0,c2=0,c3=0, d0=0,d1=0,d2=0,d3=0;
    int e = beg;
    for (; e + 3 < end; e += 4) {
      uint2 u0 = *(const uint2*)(h + (size_t)ss[e + 0] * DD + l32 * 4);
      uint2 u1 = *(const uint2*)(h + (size_t)ss[e + 1] * DD + l32 * 4);
      uint2 u2 = *(const uint2*)(h + (size_t)ss[e + 2] * DD + l32 * 4);
      uint2 u3 = *(const uint2*)(h + (size_t)ss[e + 3] * DD + l32 * 4);
      a0 += b2f((ushort)u0.x); a1 += b2f((ushort)(u0.x >> 16));
      a2 += b2f((ushort)u0.y); a3 += b2f((ushort)(u0.y >> 16));
      b0 += b2f((ushort)u1.x); b1 += b2f((ushort)(u1.x >> 16));
      b2 += b2f((ushort)u1.y); b3 += b2f((ushort)(u1.y >> 16));
      c0 += b2f((ushort)u2.x); c1 += b2f((ushort)(u2.x >> 16));
      c2 += b2f((ushort)u2.y); c3 += b2f((ushort)(u2.y >> 16));
      d0 += b2f((ushort)u3.x); d1 += b2f((ushort)(u3.x >> 16));
      d2 += b2f((ushort)u3.y); d3 += b2f((ushort)(u3.y >> 16));
    }
    for (; e < end; ++e) {
      uint2 u0 = *(const uint2*)(h + (size_t)ss[e] * DD + l32 * 4);
      a0 += b2f((ushort)u0.x); a1 += b2f((ushort)(u0.x >> 16));
      a2 += b2f((ushort)u0.y); a3 += b2f((ushort)(u0.y >> 16));
    }
    float w = inv_deg[v];
    float f0 = (a0 + b0) + (c0 + d0);
    float f1 = (a1 + b1) + (c1 + d1);
    float f2 = (a2 + b2) + (c2 + d2);
    float f3 = (a3 + b3) + (c3 + d3);
    f0 *= w; f1 *= w; f2 *= w; f3 *= w;
    uint2 p;
    p.x = (uint)f2b(f0) | ((uint)f2b(f1) << 16);
    p.y = (uint)f2b(f2) | ((uint)f2b(f3) << 16);
    *(uint2*)(hN + (size_t)v * DD + l32 * 4) = p;
  }
}

// h_out = relu([hA|hN] @ Wt^T + bias); MFMA bf16, fp32 acc; in-place safe on hA.
__global__ __launch_bounds__(256) void k_gemm_mfma(
    const ushort* __restrict__ hA, const ushort* __restrict__ hNb,
    const ushort* __restrict__ Wt, const float* __restrict__ bias,
    ushort* __restrict__ hOutB, float* __restrict__ outF, int writeF) {
  int w = threadIdx.x >> 6;
  int lane = threadIdx.x & 63;
  int row0 = blockIdx.x * 128 + w * 32;
  int r = lane & 15;
  int kg = lane >> 4;

  f32x4 acc[2][8];
#pragma unroll
  for (int mt = 0; mt < 2; ++mt)
#pragma unroll
    for (int nt = 0; nt < 8; ++nt) acc[mt][nt] = (f32x4)0.f;

  int ra0 = row0 + r;       if (ra0 >= NN) ra0 = NN - 1;
  int ra1 = row0 + 16 + r;  if (ra1 >= NN) ra1 = NN - 1;

#pragma unroll
  for (int kt = 0; kt < 8; ++kt) {
    const ushort* hs = (kt < 4) ? hA : hNb;
    int kk = (kt & 3) * 32 + kg * 8;
    short8 a0 = *(const short8*)(hs + (size_t)ra0 * DD + kk);
    short8 a1 = *(const short8*)(hs + (size_t)ra1 * DD + kk);
    int kw = kt * 32 + kg * 8;
#pragma unroll
    for (int nt = 0; nt < 8; ++nt) {
      short8 b = *(const short8*)(Wt + (size_t)(nt * 16 + r) * 256 + kw);
      acc[0][nt] = __builtin_amdgcn_mfma_f32_16x16x32_bf16(a0, b, acc[0][nt], 0, 0, 0);
      acc[1][nt] = __builtin_amdgcn_mfma_f32_16x16x32_bf16(a1, b, acc[1][nt], 0, 0, 0);
    }
  }

  float bv[8];
#pragma unroll
  for (int nt = 0; nt < 8; ++nt) bv[nt] = bias[nt * 16 + r];

  int kg4 = kg * 4;
#pragma unroll
  for (int mt = 0; mt < 2; ++mt) {
#pragma unroll
    for (int j = 0; j < 4; ++j) {
      int row = row0 + mt * 16 + kg4 + j;
      if (row < NN) {
#pragma unroll
        for (int nt = 0; nt < 8; ++nt) {
          float val = fmaxf(acc[mt][nt][j] + bv[nt], 0.f);
          hOutB[(size_t)row * DD + nt * 16 + r] = f2b(val);
          if (writeF) outF[(size_t)row * DD + nt * 16 + r] = val;
        }
      }
    }
  }
}

extern "C" void kernel_launch(void* const* d_in, const int* in_sizes, int n_in,
                              void* d_out, int out_size, void* d_ws, size_t ws_size,
                              hipStream_t stream) {
  const float* x    = (const float*)d_in[0];
  const float* Ws   = (const float*)d_in[1];
  const float* Wn   = (const float*)d_in[2];
  const float* bias = (const float*)d_in[3];
  const int*   src  = (const int*)d_in[4];
  const int*   dst  = (const int*)d_in[5];
  float* out = (float*)d_out;

  int* ws      = (int*)d_ws;
  int* deg     = ws + OFF_DEG;
  int* offs    = ws + OFF_OFFS;
  int* cur     = ws + OFF_CUR;
  int* gcur    = ws + OFF_GCUR;
  int* part    = ws + OFF_PART;
  float* inv   = (float*)(ws + OFF_INV);
  ushort* Wt   = (ushort*)(ws + OFF_WT);
  int* ssorted = ws + OFF_SS;
  ushort* hB   = (ushort*)(ws + OFF_HB);
  ushort* hNb  = (ushort*)(ws + OFF_HNB);
  int2* ebuf   = (int2*)(ws + OFF_HNB);   // aliases hNb (dead until first agg)

  // CSR build (bucketed) + conversions
  k_zero<<<(ZERO_N + 255) / 256, 256, 0, stream>>>(ws + ZERO_BASE);
  k_x2b<<<(NN * (DD / 2) + 255) / 256, 256, 0, stream>>>(x, hB);
  k_wt<<<(3 * 128 * 256 + 255) / 256, 256, 0, stream>>>(Ws, Wn, Wt);
  k_bucket<<<(NE + 4095) / 4096, 256, 0, stream>>>(src, dst, gcur, ebuf);
  k_hist2<<<NBUCK, 256, 0, stream>>>(ebuf, gcur, deg);
  k_scan1<<<NB, 256, 0, stream>>>(deg, offs, part);
  k_scan2<<<1, 128, 0, stream>>>(part);
  k_scan3<<<(NN + 255) / 256, 256, 0, stream>>>(deg, offs, part, inv);
  k_scatter2<<<NBUCK * 4, 256, 0, stream>>>(ebuf, gcur, offs, cur, ssorted);

  // 3 SAGE layers, h in bf16; final layer also writes fp32 out
  for (int l = 0; l < 3; ++l) {
    k_agg2<<<2048, 256, 0, stream>>>(hB, offs, ssorted, inv, hNb);
    k_gemm_mfma<<<(NN + 127) / 128, 256, 0, stream>>>(
        hB, hNb, Wt + (size_t)l * 256 * 128, bias + l * DD, hB, out, l == 2 ? 1 : 0);
  }
}

// Round 4
// 553.485 us; speedup vs baseline: 1.7742x; 1.1017x over previous
//
#include <hip/hip_runtime.h>

typedef __attribute__((ext_vector_type(8))) short short8;
typedef __attribute__((ext_vector_type(4))) float f32x4;

static constexpr int NN = 100000;
static constexpr int NE = 1600000;
static constexpr int DD = 128;
static constexpr int NBUCK = 196;     // 512 nodes per bucket (dst >> 9)
static constexpr int CAP = 9216;      // mean 8192 + ~11 sigma

// ws layout in 4-byte words
static constexpr int OFF_GCUR  = 0;          // 256
static constexpr int OFF_BBASE = 256;        // 256 (need NBUCK+1)
static constexpr int OFF_OFFS  = 512;        // NN+1 (+pad)
static constexpr int OFF_INV   = 100516;     // NN
static constexpr int OFF_WT    = 200520;     // 3*256*128 bf16 = 49152 words
static constexpr int OFF_SS    = 249680;     // NE
static constexpr int OFF_HB    = 1849680;    // NN*64 (h bf16)
static constexpr int OFF_HNB   = 8249680;    // NN*64 (h_neigh bf16; ebuf aliases this)

__device__ inline ushort f2b(float f) {
  uint u = __builtin_bit_cast(uint, f);
  uint r = (u + 0x7fffu + ((u >> 16) & 1u)) >> 16;
  return (ushort)r;
}
__device__ inline float b2f(ushort b) {
  uint u = ((uint)b) << 16;
  return __builtin_bit_cast(float, u);
}

__global__ void k_zero(int* p) {
  int i = blockIdx.x * blockDim.x + threadIdx.x;
  if (i < 256) p[i] = 0;
}

__global__ void k_x2b(const float* __restrict__ x, ushort* __restrict__ hb) {
  int i = blockIdx.x * blockDim.x + threadIdx.x;
  if (i < NN * (DD / 2)) {
    float2 v = *(const float2*)(x + (size_t)i * 2);
    uint p = (uint)f2b(v.x) | ((uint)f2b(v.y) << 16);
    *(uint*)(hb + (size_t)i * 2) = p;
  }
}

// W^T concat: Wt[l][col][k], k<128 -> Ws[l][k][col], k>=128 -> Wn[l][k-128][col]
__global__ void k_wt(const float* __restrict__ Ws, const float* __restrict__ Wn,
                     ushort* __restrict__ Wt) {
  int i = blockIdx.x * blockDim.x + threadIdx.x;
  if (i < 3 * 128 * 256) {
    int l = i >> 15;
    int rem = i & 32767;
    int col = rem >> 8;
    int k = rem & 255;
    float v = (k < 128) ? Ws[((size_t)l * 128 + k) * 128 + col]
                        : Wn[((size_t)l * 128 + (k - 128)) * 128 + col];
    Wt[i] = f2b(v);
  }
}

// Pass 1: bucket edges by dst>>9 into fixed-stride regions of ebuf
__global__ __launch_bounds__(256) void k_bucket(const int* __restrict__ src,
                                                const int* __restrict__ dst,
                                                int* __restrict__ gcur,
                                                int2* __restrict__ ebuf) {
  __shared__ int cnt[NBUCK], base[NBUCK];
  int t = threadIdx.x;
  int b0 = blockIdx.x * 4096;
  if (t < NBUCK) cnt[t] = 0;
  __syncthreads();
  int dv[16], pv[16];
#pragma unroll
  for (int j = 0; j < 16; ++j) {
    int idx = b0 + j * 256 + t;
    if (idx < NE) {
      int d = dst[idx];
      dv[j] = d;
      pv[j] = atomicAdd(&cnt[d >> 9], 1);
    } else dv[j] = -1;
  }
  __syncthreads();
  if (t < NBUCK) base[t] = atomicAdd(&gcur[t], cnt[t]);
  __syncthreads();
#pragma unroll
  for (int j = 0; j < 16; ++j) {
    if (dv[j] >= 0) {
      int idx = b0 + j * 256 + t;
      int b = dv[j] >> 9;
      int2 pr; pr.x = src[idx]; pr.y = dv[j];
      ebuf[(size_t)b * CAP + base[b] + pv[j]] = pr;
    }
  }
}

// exclusive scan over bucket counts -> bbase[0..NBUCK]
__global__ void k_bscan(const int* __restrict__ gcur, int* __restrict__ bbase) {
  __shared__ int sc[256];
  int t = threadIdx.x;
  int v = (t < NBUCK) ? gcur[t] : 0;
  sc[t] = v;
  __syncthreads();
  for (int off = 1; off < 256; off <<= 1) {
    int u = (t >= off) ? sc[t - off] : 0;
    __syncthreads();
    sc[t] += u;
    __syncthreads();
  }
  if (t < NBUCK) bbase[t] = sc[t] - v;
  if (t == 255) bbase[NBUCK] = sc[255];
}

// Pass 2 (fused): per-bucket hist -> offs/inv -> LDS counting sort -> streamed ss
__global__ __launch_bounds__(256) void k_sort(const int2* __restrict__ ebuf,
                                              const int* __restrict__ bbase,
                                              int* __restrict__ offs,
                                              float* __restrict__ inv,
                                              int* __restrict__ ss) {
  __shared__ int cnt[512];
  __shared__ int sbase[512];
  __shared__ int scan[256];
  __shared__ int sarr[CAP];
  int b = blockIdx.x, t = threadIdx.x;
  int base0 = bbase[b];
  int n = bbase[b + 1] - base0;
  cnt[t] = 0; cnt[t + 256] = 0;
  __syncthreads();
  const int2* eb = ebuf + (size_t)b * CAP;
  for (int i = t; i < n; i += 256) atomicAdd(&cnt[eb[i].y & 511], 1);
  __syncthreads();
  int c0 = cnt[2 * t], c1 = cnt[2 * t + 1];
  int s = c0 + c1;
  scan[t] = s;
  __syncthreads();
  for (int off = 1; off < 256; off <<= 1) {
    int u = (t >= off) ? scan[t - off] : 0;
    __syncthreads();
    scan[t] += u;
    __syncthreads();
  }
  int eb2 = scan[t] - s;
  sbase[2 * t] = eb2;
  sbase[2 * t + 1] = eb2 + c0;
  // node outputs: offs + inv_deg
  int g0 = b * 512 + 2 * t, g1 = g0 + 1;
  if (g0 < NN) {
    offs[g0] = base0 + eb2;
    inv[g0] = 1.0f / (float)(c0 > 1 ? c0 : 1);
  }
  if (g1 < NN) {
    offs[g1] = base0 + eb2 + c0;
    inv[g1] = 1.0f / (float)(c1 > 1 ? c1 : 1);
  }
  if (b == NBUCK - 1 && t == 0) offs[NN] = NE;
  // reuse cnt as cursor
  cnt[2 * t] = 0; cnt[2 * t + 1] = 0;
  __syncthreads();
  for (int i = t; i < n; i += 256) {
    int2 e = eb[i];
    int ln = e.y & 511;
    int p = sbase[ln] + atomicAdd(&cnt[ln], 1);
    sarr[p] = e.x;
  }
  __syncthreads();
  for (int i = t; i < n; i += 256) ss[base0 + i] = sarr[i];
}

// 4 nodes per wave (16 lanes/row, uint4 = 8 bf16/lane), unroll 8, fp32 accumulate
__global__ __launch_bounds__(256) void k_agg3(const ushort* __restrict__ h,
                                              const int* __restrict__ offs,
                                              const int* __restrict__ ss,
                                              const float* __restrict__ inv_deg,
                                              ushort* __restrict__ hN) {
  int gid = blockIdx.x * blockDim.x + threadIdx.x;
  int wid = gid >> 6;
  int lane = threadIdx.x & 63;
  int q = lane >> 4, l16 = lane & 15;
  int v = wid * 4 + q;             // grid sized so wid < NN/4 exactly
  int beg = offs[v], end = offs[v + 1];
  float a0 = 0, a1 = 0, a2 = 0, a3 = 0, a4 = 0, a5 = 0, a6 = 0, a7 = 0;
  const ushort* hp = h + (size_t)l16 * 8;
#define ACC8(u) { a0 += b2f((ushort)u.x); a1 += b2f((ushort)(u.x >> 16)); \
                  a2 += b2f((ushort)u.y); a3 += b2f((ushort)(u.y >> 16)); \
                  a4 += b2f((ushort)u.z); a5 += b2f((ushort)(u.z >> 16)); \
                  a6 += b2f((ushort)u.w); a7 += b2f((ushort)(u.w >> 16)); }
  int e = beg;
  for (; e + 7 < end; e += 8) {
    uint4 u0 = *(const uint4*)(hp + (size_t)ss[e + 0] * DD);
    uint4 u1 = *(const uint4*)(hp + (size_t)ss[e + 1] * DD);
    uint4 u2 = *(const uint4*)(hp + (size_t)ss[e + 2] * DD);
    uint4 u3 = *(const uint4*)(hp + (size_t)ss[e + 3] * DD);
    uint4 u4 = *(const uint4*)(hp + (size_t)ss[e + 4] * DD);
    uint4 u5 = *(const uint4*)(hp + (size_t)ss[e + 5] * DD);
    uint4 u6 = *(const uint4*)(hp + (size_t)ss[e + 6] * DD);
    uint4 u7 = *(const uint4*)(hp + (size_t)ss[e + 7] * DD);
    ACC8(u0) ACC8(u1) ACC8(u2) ACC8(u3) ACC8(u4) ACC8(u5) ACC8(u6) ACC8(u7)
  }
  for (; e < end; ++e) {
    uint4 u0 = *(const uint4*)(hp + (size_t)ss[e] * DD);
    ACC8(u0)
  }
#undef ACC8
  float w = inv_deg[v];
  a0 *= w; a1 *= w; a2 *= w; a3 *= w; a4 *= w; a5 *= w; a6 *= w; a7 *= w;
  uint4 p;
  p.x = (uint)f2b(a0) | ((uint)f2b(a1) << 16);
  p.y = (uint)f2b(a2) | ((uint)f2b(a3) << 16);
  p.z = (uint)f2b(a4) | ((uint)f2b(a5) << 16);
  p.w = (uint)f2b(a6) | ((uint)f2b(a7) << 16);
  *(uint4*)(hN + (size_t)v * DD + l16 * 8) = p;
}

// h_out = relu([hA|hN] @ Wt^T + bias); MFMA bf16, fp32 acc; in-place safe on hA.
__global__ __launch_bounds__(256) void k_gemm_mfma(
    const ushort* __restrict__ hA, const ushort* __restrict__ hNb,
    const ushort* __restrict__ Wt, const float* __restrict__ bias,
    ushort* __restrict__ hOutB, float* __restrict__ outF, int writeF) {
  int w = threadIdx.x >> 6;
  int lane = threadIdx.x & 63;
  int row0 = blockIdx.x * 128 + w * 32;
  int r = lane & 15;
  int kg = lane >> 4;

  f32x4 acc[2][8];
#pragma unroll
  for (int mt = 0; mt < 2; ++mt)
#pragma unroll
    for (int nt = 0; nt < 8; ++nt) acc[mt][nt] = (f32x4)0.f;

  int ra0 = row0 + r;       if (ra0 >= NN) ra0 = NN - 1;
  int ra1 = row0 + 16 + r;  if (ra1 >= NN) ra1 = NN - 1;

#pragma unroll
  for (int kt = 0; kt < 8; ++kt) {
    const ushort* hs = (kt < 4) ? hA : hNb;
    int kk = (kt & 3) * 32 + kg * 8;
    short8 a0 = *(const short8*)(hs + (size_t)ra0 * DD + kk);
    short8 a1 = *(const short8*)(hs + (size_t)ra1 * DD + kk);
    int kw = kt * 32 + kg * 8;
#pragma unroll
    for (int nt = 0; nt < 8; ++nt) {
      short8 b = *(const short8*)(Wt + (size_t)(nt * 16 + r) * 256 + kw);
      acc[0][nt] = __builtin_amdgcn_mfma_f32_16x16x32_bf16(a0, b, acc[0][nt], 0, 0, 0);
      acc[1][nt] = __builtin_amdgcn_mfma_f32_16x16x32_bf16(a1, b, acc[1][nt], 0, 0, 0);
    }
  }

  float bv[8];
#pragma unroll
  for (int nt = 0; nt < 8; ++nt) bv[nt] = bias[nt * 16 + r];

  int kg4 = kg * 4;
#pragma unroll
  for (int mt = 0; mt < 2; ++mt) {
#pragma unroll
    for (int j = 0; j < 4; ++j) {
      int row = row0 + mt * 16 + kg4 + j;
      if (row < NN) {
#pragma unroll
        for (int nt = 0; nt < 8; ++nt) {
          float val = fmaxf(acc[mt][nt][j] + bv[nt], 0.f);
          hOutB[(size_t)row * DD + nt * 16 + r] = f2b(val);
          if (writeF) outF[(size_t)row * DD + nt * 16 + r] = val;
        }
      }
    }
  }
}

extern "C" void kernel_launch(void* const* d_in, const int* in_sizes, int n_in,
                              void* d_out, int out_size, void* d_ws, size_t ws_size,
                              hipStream_t stream) {
  const float* x    = (const float*)d_in[0];
  const float* Ws   = (const float*)d_in[1];
  const float* Wn   = (const float*)d_in[2];
  const float* bias = (const float*)d_in[3];
  const int*   src  = (const int*)d_in[4];
  const int*   dst  = (const int*)d_in[5];
  float* out = (float*)d_out;

  int* ws      = (int*)d_ws;
  int* gcur    = ws + OFF_GCUR;
  int* bbase   = ws + OFF_BBASE;
  int* offs    = ws + OFF_OFFS;
  float* inv   = (float*)(ws + OFF_INV);
  ushort* Wt   = (ushort*)(ws + OFF_WT);
  int* ssorted = ws + OFF_SS;
  ushort* hB   = (ushort*)(ws + OFF_HB);
  ushort* hNb  = (ushort*)(ws + OFF_HNB);
  int2* ebuf   = (int2*)(ws + OFF_HNB);   // aliases hNb (dead until first agg)

  // CSR build (bucket -> scan -> in-LDS sort) + conversions
  k_zero<<<1, 256, 0, stream>>>(gcur);
  k_x2b<<<(NN * (DD / 2) + 255) / 256, 256, 0, stream>>>(x, hB);
  k_wt<<<(3 * 128 * 256 + 255) / 256, 256, 0, stream>>>(Ws, Wn, Wt);
  k_bucket<<<(NE + 4095) / 4096, 256, 0, stream>>>(src, dst, gcur, ebuf);
  k_bscan<<<1, 256, 0, stream>>>(gcur, bbase);
  k_sort<<<NBUCK, 256, 0, stream>>>(ebuf, bbase, offs, inv, ssorted);

  // 3 SAGE layers, h in bf16; final layer also writes fp32 out
  for (int l = 0; l < 3; ++l) {
    k_agg3<<<NN / 4 / 4, 256, 0, stream>>>(hB, offs, ssorted, inv, hNb);
    k_gemm_mfma<<<(NN + 127) / 128, 256, 0, stream>>>(
        hB, hNb, Wt + (size_t)l * 256 * 128, bias + l * DD, hB, out, l == 2 ? 1 : 0);
  }
}

// Round 7
// 531.283 us; speedup vs baseline: 1.8483x; 1.0418x over previous
//
#include <hip/hip_runtime.h>

typedef __attribute__((ext_vector_type(8))) short short8;
typedef __attribute__((ext_vector_type(4))) float f32x4;

static constexpr int NN = 100000;
static constexpr int NE = 1600000;
static constexpr int DD = 128;
static constexpr int NBUCK = 196;     // 512 nodes per bucket (dst >> 9)
static constexpr int CAP = 9216;      // mean 8192 + ~11 sigma

// ws layout in 4-byte words
static constexpr int OFF_GCUR  = 0;          // 256
static constexpr int OFF_BBASE = 256;        // 256 (need NBUCK+1)
static constexpr int OFF_OFFS  = 512;        // NN+1 (+pad)
static constexpr int OFF_INV   = 100516;     // NN
static constexpr int OFF_WT    = 200520;     // 3*8*128*32 bf16 = 49152 words
static constexpr int OFF_SS    = 249680;     // NE
static constexpr int OFF_HB    = 1849680;    // NN*64 (h bf16)
static constexpr int OFF_HNB   = 8249680;    // NN*64 (h_neigh bf16; ebuf aliases this)

__device__ inline ushort f2b(float f) {
  uint u = __builtin_bit_cast(uint, f);
  uint r = (u + 0x7fffu + ((u >> 16) & 1u)) >> 16;
  return (ushort)r;
}
__device__ inline float b2f(ushort b) {
  uint u = ((uint)b) << 16;
  return __builtin_bit_cast(float, u);
}

__global__ void k_zero(int* p) {
  int i = blockIdx.x * blockDim.x + threadIdx.x;
  if (i < 256) p[i] = 0;
}

__global__ void k_x2b(const float* __restrict__ x, ushort* __restrict__ hb) {
  int i = blockIdx.x * blockDim.x + threadIdx.x;
  if (i < NN * (DD / 2)) {
    float2 v = *(const float2*)(x + (size_t)i * 2);
    uint p = (uint)f2b(v.x) | ((uint)f2b(v.y) << 16);
    *(uint*)(hb + (size_t)i * 2) = p;
  }
}

// Fragment-major packed W^T (col is 7 bits!):
// WtP[((l*8+kt)*128+col)*32 + kg*8 + j] = W[l][kt*32+kg*8+j][col]
// where W = [Ws | Wn] along k (k<128 -> Ws, else Wn). 3*32768 ushorts total.
__global__ void k_wt(const float* __restrict__ Ws, const float* __restrict__ Wn,
                     ushort* __restrict__ WtP) {
  int i = blockIdx.x * blockDim.x + threadIdx.x;
  if (i < 3 * 8 * 128 * 32) {
    int j = i & 7;
    int kg = (i >> 3) & 3;
    int col = (i >> 5) & 127;
    int kt = (i >> 12) & 7;
    int l = i >> 15;
    int k = kt * 32 + kg * 8 + j;
    float v = (k < 128) ? Ws[((size_t)l * 128 + k) * 128 + col]
                        : Wn[((size_t)l * 128 + (k - 128)) * 128 + col];
    WtP[i] = f2b(v);
  }
}

// Pass 1: bucket edges by dst>>9 into fixed-stride regions of ebuf
__global__ __launch_bounds__(256) void k_bucket(const int* __restrict__ src,
                                                const int* __restrict__ dst,
                                                int* __restrict__ gcur,
                                                int2* __restrict__ ebuf) {
  __shared__ int cnt[NBUCK], base[NBUCK];
  int t = threadIdx.x;
  int b0 = blockIdx.x * 4096;
  if (t < NBUCK) cnt[t] = 0;
  __syncthreads();
  int dv[16], pv[16];
#pragma unroll
  for (int j = 0; j < 16; ++j) {
    int idx = b0 + j * 256 + t;
    if (idx < NE) {
      int d = dst[idx];
      dv[j] = d;
      pv[j] = atomicAdd(&cnt[d >> 9], 1);
    } else dv[j] = -1;
  }
  __syncthreads();
  if (t < NBUCK) base[t] = atomicAdd(&gcur[t], cnt[t]);
  __syncthreads();
#pragma unroll
  for (int j = 0; j < 16; ++j) {
    if (dv[j] >= 0) {
      int idx = b0 + j * 256 + t;
      int b = dv[j] >> 9;
      int2 pr; pr.x = src[idx]; pr.y = dv[j];
      ebuf[(size_t)b * CAP + base[b] + pv[j]] = pr;
    }
  }
}

// exclusive scan over bucket counts -> bbase[0..NBUCK]
__global__ void k_bscan(const int* __restrict__ gcur, int* __restrict__ bbase) {
  __shared__ int sc[256];
  int t = threadIdx.x;
  int v = (t < NBUCK) ? gcur[t] : 0;
  sc[t] = v;
  __syncthreads();
  for (int off = 1; off < 256; off <<= 1) {
    int u = (t >= off) ? sc[t - off] : 0;
    __syncthreads();
    sc[t] += u;
    __syncthreads();
  }
  if (t < NBUCK) bbase[t] = sc[t] - v;
  if (t == 255) bbase[NBUCK] = sc[255];
}

// Pass 2 (fused): per-bucket hist -> offs/inv -> LDS counting sort -> streamed ss
__global__ __launch_bounds__(256) void k_sort(const int2* __restrict__ ebuf,
                                              const int* __restrict__ bbase,
                                              int* __restrict__ offs,
                                              float* __restrict__ inv,
                                              int* __restrict__ ss) {
  __shared__ int cnt[512];
  __shared__ int sbase[512];
  __shared__ int scan[256];
  __shared__ int sarr[CAP];
  int b = blockIdx.x, t = threadIdx.x;
  int base0 = bbase[b];
  int n = bbase[b + 1] - base0;
  cnt[t] = 0; cnt[t + 256] = 0;
  __syncthreads();
  const int2* eb = ebuf + (size_t)b * CAP;
  for (int i = t; i < n; i += 256) atomicAdd(&cnt[eb[i].y & 511], 1);
  __syncthreads();
  int c0 = cnt[2 * t], c1 = cnt[2 * t + 1];
  int s = c0 + c1;
  scan[t] = s;
  __syncthreads();
  for (int off = 1; off < 256; off <<= 1) {
    int u = (t >= off) ? scan[t - off] : 0;
    __syncthreads();
    scan[t] += u;
    __syncthreads();
  }
  int eb2 = scan[t] - s;
  sbase[2 * t] = eb2;
  sbase[2 * t + 1] = eb2 + c0;
  int g0 = b * 512 + 2 * t, g1 = g0 + 1;
  if (g0 < NN) {
    offs[g0] = base0 + eb2;
    inv[g0] = 1.0f / (float)(c0 > 1 ? c0 : 1);
  }
  if (g1 < NN) {
    offs[g1] = base0 + eb2 + c0;
    inv[g1] = 1.0f / (float)(c1 > 1 ? c1 : 1);
  }
  if (b == NBUCK - 1 && t == 0) offs[NN] = NE;
  cnt[2 * t] = 0; cnt[2 * t + 1] = 0;
  __syncthreads();
  for (int i = t; i < n; i += 256) {
    int2 e = eb[i];
    int ln = e.y & 511;
    int p = sbase[ln] + atomicAdd(&cnt[ln], 1);
    sarr[p] = e.x;
  }
  __syncthreads();
  for (int i = t; i < n; i += 256) ss[base0 + i] = sarr[i];
}

// 4 nodes per wave (16 lanes/row, uint4 = 8 bf16/lane), unroll 8, fp32 accumulate
__global__ __launch_bounds__(256) void k_agg3(const ushort* __restrict__ h,
                                              const int* __restrict__ offs,
                                              const int* __restrict__ ss,
                                              const float* __restrict__ inv_deg,
                                              ushort* __restrict__ hN) {
  int gid = blockIdx.x * blockDim.x + threadIdx.x;
  int wid = gid >> 6;
  int lane = threadIdx.x & 63;
  int q = lane >> 4, l16 = lane & 15;
  int v = wid * 4 + q;
  int beg = offs[v], end = offs[v + 1];
  float a0 = 0, a1 = 0, a2 = 0, a3 = 0, a4 = 0, a5 = 0, a6 = 0, a7 = 0;
  const ushort* hp = h + (size_t)l16 * 8;
#define ACC8(u) { a0 += b2f((ushort)u.x); a1 += b2f((ushort)(u.x >> 16)); \
                  a2 += b2f((ushort)u.y); a3 += b2f((ushort)(u.y >> 16)); \
                  a4 += b2f((ushort)u.z); a5 += b2f((ushort)(u.z >> 16)); \
                  a6 += b2f((ushort)u.w); a7 += b2f((ushort)(u.w >> 16)); }
  int e = beg;
  for (; e + 7 < end; e += 8) {
    uint4 u0 = *(const uint4*)(hp + (size_t)ss[e + 0] * DD);
    uint4 u1 = *(const uint4*)(hp + (size_t)ss[e + 1] * DD);
    uint4 u2 = *(const uint4*)(hp + (size_t)ss[e + 2] * DD);
    uint4 u3 = *(const uint4*)(hp + (size_t)ss[e + 3] * DD);
    uint4 u4 = *(const uint4*)(hp + (size_t)ss[e + 4] * DD);
    uint4 u5 = *(const uint4*)(hp + (size_t)ss[e + 5] * DD);
    uint4 u6 = *(const uint4*)(hp + (size_t)ss[e + 6] * DD);
    uint4 u7 = *(const uint4*)(hp + (size_t)ss[e + 7] * DD);
    ACC8(u0) ACC8(u1) ACC8(u2) ACC8(u3) ACC8(u4) ACC8(u5) ACC8(u6) ACC8(u7)
  }
  for (; e < end; ++e) {
    uint4 u0 = *(const uint4*)(hp + (size_t)ss[e] * DD);
    ACC8(u0)
  }
#undef ACC8
  float w = inv_deg[v];
  a0 *= w; a1 *= w; a2 *= w; a3 *= w; a4 *= w; a5 *= w; a6 *= w; a7 *= w;
  uint4 p;
  p.x = (uint)f2b(a0) | ((uint)f2b(a1) << 16);
  p.y = (uint)f2b(a2) | ((uint)f2b(a3) << 16);
  p.z = (uint)f2b(a4) | ((uint)f2b(a5) << 16);
  p.w = (uint)f2b(a6) | ((uint)f2b(a7) << 16);
  *(uint4*)(hN + (size_t)v * DD + l16 * 8) = p;
}

// h_out = relu([hA|hN] @ W + bias), 128 rows/block, wave w = 32-col quarter.
// B-fragments live in registers for the whole block (loaded once).
// In-place safe: accs for 64 rows computed (reads done) -> barrier -> stores.
__global__ __launch_bounds__(256) void k_gemm2(
    const ushort* __restrict__ hA, const ushort* __restrict__ hNb,
    const ushort* __restrict__ WtP, const float* __restrict__ bias,
    ushort* __restrict__ hOutB, float* __restrict__ outF, int writeF) {
  int w = threadIdx.x >> 6;
  int lane = threadIdx.x & 63;
  int r = lane & 15, kg = lane >> 4;
  int colbase = w * 32;

  short8 bfrag[8][2];
#pragma unroll
  for (int kt = 0; kt < 8; ++kt)
#pragma unroll
    for (int nt = 0; nt < 2; ++nt) {
      int col = colbase + nt * 16 + r;
      bfrag[kt][nt] = *(const short8*)(WtP + ((size_t)(kt * 128 + col) * 4 + kg) * 8);
    }

  float bv[2];
  bv[0] = bias[colbase + r];
  bv[1] = bias[colbase + 16 + r];

  int rowblk = blockIdx.x * 128;
#pragma unroll 1
  for (int half = 0; half < 2; ++half) {
    f32x4 acc[2][2][2];  // [it][mt][nt]
#pragma unroll
    for (int it = 0; it < 2; ++it) {
      int row0 = rowblk + half * 64 + it * 32;
      int ra0 = row0 + r;      if (ra0 > NN - 1) ra0 = NN - 1;
      int ra1 = row0 + 16 + r; if (ra1 > NN - 1) ra1 = NN - 1;
#pragma unroll
      for (int mt = 0; mt < 2; ++mt)
#pragma unroll
        for (int nt = 0; nt < 2; ++nt) acc[it][mt][nt] = (f32x4)0.f;
#pragma unroll
      for (int kt = 0; kt < 8; ++kt) {
        const ushort* hs = (kt < 4) ? hA : hNb;
        int kk = (kt & 3) * 32 + kg * 8;
        short8 a0 = *(const short8*)(hs + (size_t)ra0 * DD + kk);
        short8 a1 = *(const short8*)(hs + (size_t)ra1 * DD + kk);
        acc[it][0][0] = __builtin_amdgcn_mfma_f32_16x16x32_bf16(a0, bfrag[kt][0], acc[it][0][0], 0, 0, 0);
        acc[it][0][1] = __builtin_amdgcn_mfma_f32_16x16x32_bf16(a0, bfrag[kt][1], acc[it][0][1], 0, 0, 0);
        acc[it][1][0] = __builtin_amdgcn_mfma_f32_16x16x32_bf16(a1, bfrag[kt][0], acc[it][1][0], 0, 0, 0);
        acc[it][1][1] = __builtin_amdgcn_mfma_f32_16x16x32_bf16(a1, bfrag[kt][1], acc[it][1][1], 0, 0, 0);
      }
    }
    __syncthreads();   // all reads of these 64 rows complete before any write
#pragma unroll
    for (int it = 0; it < 2; ++it) {
      int row0 = rowblk + half * 64 + it * 32;
#pragma unroll
      for (int mt = 0; mt < 2; ++mt) {
#pragma unroll
        for (int j = 0; j < 4; ++j) {
          int row = row0 + mt * 16 + kg * 4 + j;
          if (row < NN) {
#pragma unroll
            for (int nt = 0; nt < 2; ++nt) {
              float val = fmaxf(acc[it][mt][nt][j] + bv[nt], 0.f);
              int col = colbase + nt * 16 + r;
              hOutB[(size_t)row * DD + col] = f2b(val);
              if (writeF) outF[(size_t)row * DD + col] = val;
            }
          }
        }
      }
    }
    __syncthreads();   // writes done before next half's (different) rows proceed
  }
}

extern "C" void kernel_launch(void* const* d_in, const int* in_sizes, int n_in,
                              void* d_out, int out_size, void* d_ws, size_t ws_size,
                              hipStream_t stream) {
  const float* x    = (const float*)d_in[0];
  const float* Ws   = (const float*)d_in[1];
  const float* Wn   = (const float*)d_in[2];
  const float* bias = (const float*)d_in[3];
  const int*   src  = (const int*)d_in[4];
  const int*   dst  = (const int*)d_in[5];
  float* out = (float*)d_out;

  int* ws      = (int*)d_ws;
  int* gcur    = ws + OFF_GCUR;
  int* bbase   = ws + OFF_BBASE;
  int* offs    = ws + OFF_OFFS;
  float* inv   = (float*)(ws + OFF_INV);
  ushort* WtP  = (ushort*)(ws + OFF_WT);
  int* ssorted = ws + OFF_SS;
  ushort* hB   = (ushort*)(ws + OFF_HB);
  ushort* hNb  = (ushort*)(ws + OFF_HNB);
  int2* ebuf   = (int2*)(ws + OFF_HNB);   // aliases hNb (dead until first agg)

  // CSR build (bucket -> scan -> in-LDS sort) + conversions
  k_zero<<<1, 256, 0, stream>>>(gcur);
  k_x2b<<<(NN * (DD / 2) + 255) / 256, 256, 0, stream>>>(x, hB);
  k_wt<<<(3 * 8 * 128 * 32 + 255) / 256, 256, 0, stream>>>(Ws, Wn, WtP);
  k_bucket<<<(NE + 4095) / 4096, 256, 0, stream>>>(src, dst, gcur, ebuf);
  k_bscan<<<1, 256, 0, stream>>>(gcur, bbase);
  k_sort<<<NBUCK, 256, 0, stream>>>(ebuf, bbase, offs, inv, ssorted);

  // 3 SAGE layers, h in bf16; final layer also writes fp32 out
  for (int l = 0; l < 3; ++l) {
    k_agg3<<<NN / 4 / 4, 256, 0, stream>>>(hB, offs, ssorted, inv, hNb);
    k_gemm2<<<(NN + 127) / 128, 256, 0, stream>>>(
        hB, hNb, WtP + (size_t)l * 8 * 128 * 32, bias + l * DD, hB, out, l == 2 ? 1 : 0);
  }
}